// Round 6
// baseline (231.521 us; speedup 1.0000x reference)
//
#include <hip/hip_runtime.h>
#include <hip/hip_fp16.h>

// Problem constants (H=W=2048, C=3, KSIZE=2, SIGMA=2, ITERATIONS=2)
#define Hh 2048
#define Ww 2048
#define HW (2048 * 2048)
constexpr int REG = 2045;              // Hv = Wv = H - 2*KSIZE + 1
constexpr int RBASE = 2 * 2045 * 2045; // i-plane stride of `off` in elements
constexpr int SWAP_D2 = 589824;        // 768^2
constexpr int CLEAN_D2 = 586756;       // 766^2
// A[p] is consumed by some non-clean blur output iff dist(p) >= 766 - 8*sqrt(2)
// = 754.686 (754.686^2 = 569551). Blocks strictly inside this circle can skip
// everything: their A values only ever contribute to outputs that compose
// SELECTS (not blends) from img, so even NaN garbage is harmless.
constexpr int SKIP_D2 = 569000;

// Gaussian kernel sigma=2, truncate=4 -> radius 8, normalized (precomputed)
__device__ __constant__ float GK[17] = {
    6.691628e-05f, 4.363490e-04f, 2.215963e-03f, 8.764304e-03f,
    2.699596e-02f, 6.475994e-02f, 1.209875e-01f, 1.760358e-01f,
    1.9947466e-01f, 1.760358e-01f, 1.209875e-01f, 6.475994e-02f,
    2.699596e-02f, 8.764304e-03f, 2.215963e-03f, 4.363490e-04f,
    6.691628e-05f};

__device__ __forceinline__ int clampi(int v, int lo, int hi) {
  return v < lo ? lo : (v > hi ? hi : v);
}

// ---------------------------------------------------------------------------
// Pass 1: gather-formulated glass swap + fp16 planar repack (unchanged).
// ---------------------------------------------------------------------------
constexpr int TX = 32, TY = 8;
constexpr int HX = TX + 3, HY = TY + 3;  // 35 x 11 offsets halo

__global__ __launch_bounds__(256) void swap_gather(
    const float* __restrict__ img, const int* __restrict__ off,
    __half* __restrict__ A) {
  __shared__ unsigned sh[HY * HX];
  __shared__ __align__(16) float simg[12 * 108];  // 12 rows x 36 px x 3 ch
  int x0 = blockIdx.x * TX, y0 = blockIdx.y * TY;
  int tx = threadIdx.x & 31, ty = threadIdx.x >> 5;
  int px = x0 + tx, py = y0 + ty;
  int plin = py * Ww + px;

  // Deep clean interior: A never consumed -> skip the whole block.
  int bxx = max(abs(1024 - x0), abs(1024 - (x0 + TX - 1)));
  int bxy = max(abs(1024 - y0), abs(1024 - (y0 + TY - 1)));
  if (bxx * bxx + bxy * bxy < SKIP_D2) return;

  float r, g, b;
  int mxx = max(abs(1024 - (x0 - 1)), abs(1024 - (x0 + TX + 1)));
  int mxy = max(abs(1024 - (y0 - 1)), abs(1024 - (y0 + TY + 1)));
  if (mxx * mxx + mxy * mxy >= SWAP_D2) {
    // ---- stage packed offsets halo (rows y0-1..y0+9, cols x0-1..x0+33) ----
    for (int e = threadIdx.x; e < HY * HX; e += 256) {
      int ly = e / HX, lx = e - ly * HX;
      int qy = y0 - 1 + ly, qx = x0 - 1 + lx;
      unsigned v = 0xFFFFFFFFu;
      int dcx = 1024 - qx, dcy = 1024 - qy;
      if (qy >= 2 && qy <= 2046 && qx >= 2 && qx <= 2046 &&
          dcx * dcx + dcy * dcy >= SWAP_D2) {
        int base = ((qy - 2) * REG + (qx - 2)) * 2;
        const int2 a0 = *(const int2*)&off[base];          // {dh0, dw0}
        const int2 a1 = *(const int2*)&off[RBASE + base];  // {dh1, dw1}
        v = (unsigned)(a0.y + 2) | ((unsigned)(a0.x + 2) << 8) |
            ((unsigned)(a1.y + 2) << 16) | ((unsigned)(a1.x + 2) << 24);
      }
      sh[e] = v;
    }
    // ---- stage img halo (rows y0-2..y0+9, cols x0-2..x0+33, 3 ch) ----
    if (x0 >= 2 && x0 <= 2013) {  // interior in x: coalesced float2 rows
      for (int e = threadIdx.x; e < 648; e += 256) {
        int rr = e / 54, c2 = e - rr * 54;
        int qy = clampi(y0 - 2 + rr, 0, 2047);
        *(float2*)&simg[rr * 108 + 2 * c2] =
            *(const float2*)&img[(size_t)qy * 6144 + (size_t)(x0 - 2) * 3 +
                                 2 * c2];
      }
    } else {  // x-edge blocks: scalar with per-pixel clamp (mode='nearest'
              // values are never selected; clamp only keeps reads in-bounds)
      for (int e = threadIdx.x; e < 1296; e += 256) {
        int rr = e / 108, c3 = e - rr * 108;
        int col = c3 / 3, ch = c3 - col * 3;
        int qy = clampi(y0 - 2 + rr, 0, 2047);
        int qx = clampi(x0 - 2 + col, 0, 2047);
        simg[e] = img[((size_t)qy * Ww + qx) * 3 + ch];
      }
    }
    __syncthreads();

    unsigned w[4][4];
#pragma unroll
    for (int dyi = 0; dyi < 4; ++dyi)
#pragma unroll
      for (int dxi = 0; dxi < 4; ++dxi)
        w[dyi][dxi] = sh[(ty + dyi) * HX + (tx + dxi)];

    int loff = 0;  // local offset into simg (36-wide rows)
#define CANDC(dyi, dxi) ((unsigned)((1 - (dxi)) + 2) | ((unsigned)((1 - (dyi)) + 2) << 8))
#define LOFFC(dyi, dxi) (-(1 - (dyi)) * 36 - (1 - (dxi)))
#define CAND0(dyi, dxi) \
  if ((w[dyi][dxi] & 0xFFFFu) == CANDC(dyi, dxi)) loff = LOFFC(dyi, dxi);
#define CAND1(dyi, dxi) \
  if ((w[dyi][dxi] >> 16) == CANDC(dyi, dxi)) loff = LOFFC(dyi, dxi);

    // i = 0 write2 candidates, in increasing-order sequence
    CAND0(0, 0) CAND0(0, 1) CAND0(0, 2) CAND0(0, 3)
    CAND0(1, 0) CAND0(1, 1) CAND0(1, 2) CAND0(1, 3)
    CAND0(2, 0) CAND0(2, 1) CAND0(2, 2) CAND0(2, 3)
    CAND0(3, 0) CAND0(3, 1) CAND0(3, 2) CAND0(3, 3)
    // i = 1: cands with ddy*REG+ddx >= 1, then self-write, then the rest
    CAND1(0, 0) CAND1(0, 1) CAND1(0, 2) CAND1(0, 3)
    CAND1(1, 0)
    {  // self-write (i=1 write1): src = p + off1[p]
      unsigned wc = w[1][1];
      if ((wc >> 24) != 0xFFu) {
        int dh1 = (int)((wc >> 24) & 0xFFu) - 2;
        int dw1 = (int)((wc >> 16) & 0xFFu) - 2;
        loff = dh1 * 36 + dw1;
      }
    }
    CAND1(1, 1) CAND1(1, 2) CAND1(1, 3)
    CAND1(2, 0) CAND1(2, 1) CAND1(2, 2) CAND1(2, 3)
    CAND1(3, 0) CAND1(3, 1) CAND1(3, 2) CAND1(3, 3)
#undef CANDC
#undef LOFFC
#undef CAND0
#undef CAND1

    int L = ((ty + 2) * 36 + (tx + 2) + loff) * 3;
    r = simg[L + 0];
    g = simg[L + 1];
    b = simg[L + 2];
  } else {
    // shell between SKIP and SWAP circles: plain convert
    r = img[(size_t)plin * 3 + 0];
    g = img[(size_t)plin * 3 + 1];
    b = img[(size_t)plin * 3 + 2];
  }
  A[plin] = __float2half(r);
  A[HW + plin] = __float2half(g);
  A[2 * HW + plin] = __float2half(b);
}

// ---------------------------------------------------------------------------
// Pass 2 (fused blur + compose).
// Round-6: occupancy fix. R5 counters: dur 49.6 us with HBM 19%, VALU 30%,
// occupancy 22% -> latency-bound. VGPR=76 is in the 65-128 allocation tier
// (waves/CU halve at 64/128/256) -> only 4 waves/SIMD. Fix: BTH 16->8 cuts
// per-thread state (br[3][2][2]=12 regs) to fit the <=64-VGPR tier, pinned
// via __launch_bounds__(256,8); grid 2048->4096 blocks (16 blocks/CU of
// work) so resident blocks double and barrier chains hide behind each other.
// Remap tables (16-row units) reused by splitting each 16-tile into two
// 8-tiles inheriting the parent's class (clean-parent child provably clean;
// heavy path is correct for any tile).
// ---------------------------------------------------------------------------
constexpr int BTW = 128, BTH = 8;  // output tile
constexpr int SW = BTW + 16;       // 144 staged cols
constexpr int SH = BTH + 16;       // 24 staged rows

// Per-tile-column clean-interval tables (exact, from CLEAN_D2 circle),
// in 16-row tile units:
// heavy counts/col: {128,128,128,76,58,46,38,34,34,38,46,58,76,128,128,128}
__device__ __constant__ short HPRE[17] = {0,   128, 256, 384, 460,  518,
                                          564, 602, 636, 670, 708,  754,
                                          812, 888, 1016, 1144, 1272};
__device__ __constant__ short CPRE[17] = {0,   0,   0,   0,   52,  122,
                                          204, 294, 388, 482, 572, 654,
                                          724, 776, 776, 776, 776};
__device__ __constant__ short CLO[16] = {128, 128, 128, 38, 29, 23, 19, 17,
                                         17,  19,  23,  29, 38, 128, 128, 128};
__device__ __constant__ short CCN[16] = {0,  0,  0,  52, 70, 82, 90, 94,
                                         94, 90, 82, 70, 52, 0,  0,  0};
constexpr int NHEAVY = 1272;      // 16-row units
constexpr int NCLEAN = 776;
constexpr int NH8 = 2 * NHEAVY;   // 2544 = 8 * 318 8-row heavy tiles
constexpr int NC8 = 2 * NCLEAN;   // 1552 = 8 * 194 8-row clean tiles

__global__ __launch_bounds__(256, 8) void blur_compose(
    const __half* __restrict__ A, const float* __restrict__ img,
    float* __restrict__ out) {
  int lin = blockIdx.x;  // 4096 = NH8 + NC8
  int tid = threadIdx.x;
  int txb, y0;
  bool is_clean = lin >= NH8;
  if (!is_clean) {
    int idx = (lin & 7) * 318 + (lin >> 3);  // XCD k: heavy run [318k,318k+318)
    int idx2 = idx >> 1;                     // 16-row tile index
    int c = 0;
    while (idx2 >= HPRE[c + 1]) ++c;
    int j = idx2 - HPRE[c];
    txb = c;
    int ty16 = j < CLO[c] ? j : j + CCN[c];  // skip the clean interval
    y0 = ty16 * 16 + (idx & 1) * 8;
  } else {
    int l = lin - NH8;
    int idx = (l & 7) * 194 + (l >> 3);
    int idx2 = idx >> 1;
    int c = 0;
    while (idx2 >= CPRE[c + 1]) ++c;
    txb = c;
    int ty16 = CLO[c] + (idx2 - CPRE[c]);
    y0 = ty16 * 16 + (idx & 1) * 8;
  }
  int x0 = txb * BTW;

  // Clean tile: straight float4 copy, A never touched.
  if (is_clean) {
    const float4* ip = (const float4*)(img + ((size_t)y0 * Ww + x0) * 3);
    float4* op = (float4*)(out + ((size_t)y0 * Ww + x0) * 3);
    for (int e = tid; e < 768; e += 256) {  // 8 rows x 96 float4, 3 exact
      int rr = e / 96, c4 = e - rr * 96;
      op[(size_t)rr * 1536 + c4] = ip[(size_t)rr * 1536 + c4];
    }
    return;
  }

  __shared__ __align__(16) __half S[SH * SW];  // 6.9 KB staged A (half)
  __shared__ __align__(8) __half V[BTH * SW];  // 2.3 KB vertical result (half)

  bool xin = (x0 >= 8) && (x0 + SW - 8 <= Ww);  // no x clamp needed

  float br[3][2][2];  // [channel][pair-slot][pixel-in-pair]

  for (int c = 0; c < 3; ++c) {
    const __half* Ap = A + (size_t)c * HW;
    // ---- stage A tile+halo ----
    // (safe without a leading barrier: previous channel's S readers are all
    //  behind the post-vertical barrier; horizontal only touches V.)
    if (xin) {
      for (int e = tid; e < SH * 18; e += 256) {  // 18 dwordx4 per row
        int rr = e / 18, ch = e - rr * 18;
        int ys = clampi(y0 - 8 + rr, 0, Hh - 1);  // mode='nearest'
        *(uint4*)&S[rr * SW + ch * 8] =
            *(const uint4*)&Ap[(size_t)ys * Ww + (x0 - 8) + ch * 8];
      }
    } else {
      for (int e = tid; e < SH * SW; e += 256) {
        int rr = e / SW, j = e - rr * SW;
        int ys = clampi(y0 - 8 + rr, 0, Hh - 1);
        int xs = clampi(x0 - 8 + j, 0, Ww - 1);
        S[e] = Ap[(size_t)ys * Ww + xs];
      }
    }
    __syncthreads();  // S staged, and prev channel's V readers done
    // ---- vertical 17-tap: 8 rows x 72 half2 cols = 576 items ----
    for (int e = tid; e < BTH * 72; e += 256) {
      int rr = e / 72, p = e - rr * 72;
      float s0 = 0.f, s1 = 0.f;
#pragma unroll
      for (int t = 0; t < 17; ++t) {
        float2 v = __half22float2(*(const __half2*)&S[(rr + t) * SW + 2 * p]);
        s0 += GK[t] * v.x;
        s1 += GK[t] * v.y;
      }
      *(__half2*)&V[rr * SW + 2 * p] = __float22half2_rn(make_float2(s0, s1));
    }
    __syncthreads();
    // ---- horizontal 17-tap into registers: 8 rows x 64 px-pairs ----
#pragma unroll
    for (int k = 0; k < 2; ++k) {
      int e = tid + (k << 8);  // 0..511, exact
      int rr = e >> 6, x = (e & 63) * 2;
      float f[18];
#pragma unroll
      for (int t = 0; t < 9; ++t) {
        float2 v = __half22float2(*(const __half2*)&V[rr * SW + x + 2 * t]);
        f[2 * t] = v.x;
        f[2 * t + 1] = v.y;
      }
      float s0 = 0.f, s1 = 0.f;
#pragma unroll
      for (int t = 0; t < 17; ++t) {
        s0 += GK[t] * f[t];
        s1 += GK[t] * f[t + 1];
      }
      br[c][k][0] = s0;
      br[c][k][1] = s1;
    }
  }

  // ---- single write phase: 24 contiguous bytes per pixel-pair ----
#pragma unroll
  for (int k = 0; k < 2; ++k) {
    int e = tid + (k << 8);
    int rr = e >> 6, xh = e & 63;
    int y = y0 + rr;
    int xg = x0 + 2 * xh;
    int dy = 1024 - y;
    int dy2 = dy * dy;
    float px[6];
#pragma unroll
    for (int u = 0; u < 2; ++u) {
      int xu = xg + u;
      int dx = 1024 - xu;
      bool clean = (xu >= 2 && xu <= 2046 && y >= 2 && y <= 2046 &&
                    dx * dx + dy2 < CLEAN_D2);
      int p3 = (y * Ww + xu) * 3;
      if (clean) {
        px[3 * u + 0] = img[p3 + 0];
        px[3 * u + 1] = img[p3 + 1];
        px[3 * u + 2] = img[p3 + 2];
      } else {
#pragma unroll
        for (int cc = 0; cc < 3; ++cc) {
          float v = br[cc][k][u];
          v = v < 0.f ? 0.f : (v > 255.f ? 255.f : v);
          px[3 * u + cc] = v;
        }
      }
    }
    float* ob = out + (size_t)(y * Ww + xg) * 3;
    *(float2*)&ob[0] = make_float2(px[0], px[1]);
    *(float2*)&ob[2] = make_float2(px[2], px[3]);
    *(float2*)&ob[4] = make_float2(px[4], px[5]);
  }
}

extern "C" void kernel_launch(void* const* d_in, const int* in_sizes, int n_in,
                              void* d_out, int out_size, void* d_ws,
                              size_t ws_size, hipStream_t stream) {
  const float* img = (const float*)d_in[0];
  const int* off = (const int*)d_in[1];
  float* out = (float*)d_out;

  // Workspace: A (fp16 x 3 planes, 25 MB)
  __half* A = (__half*)d_ws;

  swap_gather<<<dim3(Ww / TX, Hh / TY), 256, 0, stream>>>(img, off, A);
  blur_compose<<<NH8 + NC8, 256, 0, stream>>>(A, img, out);
}

// Round 7
// 210.174 us; speedup vs baseline: 1.1016x; 1.1016x over previous
//
#include <hip/hip_runtime.h>
#include <hip/hip_fp16.h>

// Problem constants (H=W=2048, C=3, KSIZE=2, SIGMA=2, ITERATIONS=2)
#define Hh 2048
#define Ww 2048
#define HW (2048 * 2048)
constexpr int REG = 2045;              // Hv = Wv = H - 2*KSIZE + 1
constexpr int RBASE = 2 * 2045 * 2045; // i-plane stride of `off` in elements
constexpr int SWAP_D2 = 589824;        // 768^2
constexpr int CLEAN_D2 = 586756;       // 766^2
// A[p] is consumed by some non-clean blur output iff dist(p) >= 766 - 8*sqrt(2)
// = 754.686 (754.686^2 = 569551). Blocks strictly inside this circle can skip
// everything: their A values only ever contribute to outputs that compose
// SELECTS (not blends) from img, so even NaN garbage is harmless.
constexpr int SKIP_D2 = 569000;

// Gaussian kernel sigma=2, truncate=4 -> radius 8, normalized (precomputed)
__device__ __constant__ float GK[17] = {
    6.691628e-05f, 4.363490e-04f, 2.215963e-03f, 8.764304e-03f,
    2.699596e-02f, 6.475994e-02f, 1.209875e-01f, 1.760358e-01f,
    1.9947466e-01f, 1.760358e-01f, 1.209875e-01f, 6.475994e-02f,
    2.699596e-02f, 8.764304e-03f, 2.215963e-03f, 4.363490e-04f,
    6.691628e-05f};

__device__ __forceinline__ int clampi(int v, int lo, int hi) {
  return v < lo ? lo : (v > hi ? hi : v);
}

// ---------------------------------------------------------------------------
// Pass 1: gather-formulated glass swap + fp16 planar repack (unchanged).
// ---------------------------------------------------------------------------
constexpr int TX = 32, TY = 8;
constexpr int HX = TX + 3, HY = TY + 3;  // 35 x 11 offsets halo

__global__ __launch_bounds__(256) void swap_gather(
    const float* __restrict__ img, const int* __restrict__ off,
    __half* __restrict__ A) {
  __shared__ unsigned sh[HY * HX];
  __shared__ __align__(16) float simg[12 * 108];  // 12 rows x 36 px x 3 ch
  int x0 = blockIdx.x * TX, y0 = blockIdx.y * TY;
  int tx = threadIdx.x & 31, ty = threadIdx.x >> 5;
  int px = x0 + tx, py = y0 + ty;
  int plin = py * Ww + px;

  // Deep clean interior: A never consumed -> skip the whole block.
  int bxx = max(abs(1024 - x0), abs(1024 - (x0 + TX - 1)));
  int bxy = max(abs(1024 - y0), abs(1024 - (y0 + TY - 1)));
  if (bxx * bxx + bxy * bxy < SKIP_D2) return;

  float r, g, b;
  int mxx = max(abs(1024 - (x0 - 1)), abs(1024 - (x0 + TX + 1)));
  int mxy = max(abs(1024 - (y0 - 1)), abs(1024 - (y0 + TY + 1)));
  if (mxx * mxx + mxy * mxy >= SWAP_D2) {
    // ---- stage packed offsets halo (rows y0-1..y0+9, cols x0-1..x0+33) ----
    for (int e = threadIdx.x; e < HY * HX; e += 256) {
      int ly = e / HX, lx = e - ly * HX;
      int qy = y0 - 1 + ly, qx = x0 - 1 + lx;
      unsigned v = 0xFFFFFFFFu;
      int dcx = 1024 - qx, dcy = 1024 - qy;
      if (qy >= 2 && qy <= 2046 && qx >= 2 && qx <= 2046 &&
          dcx * dcx + dcy * dcy >= SWAP_D2) {
        int base = ((qy - 2) * REG + (qx - 2)) * 2;
        const int2 a0 = *(const int2*)&off[base];          // {dh0, dw0}
        const int2 a1 = *(const int2*)&off[RBASE + base];  // {dh1, dw1}
        v = (unsigned)(a0.y + 2) | ((unsigned)(a0.x + 2) << 8) |
            ((unsigned)(a1.y + 2) << 16) | ((unsigned)(a1.x + 2) << 24);
      }
      sh[e] = v;
    }
    // ---- stage img halo (rows y0-2..y0+9, cols x0-2..x0+33, 3 ch) ----
    if (x0 >= 2 && x0 <= 2013) {  // interior in x: coalesced float2 rows
      for (int e = threadIdx.x; e < 648; e += 256) {
        int rr = e / 54, c2 = e - rr * 54;
        int qy = clampi(y0 - 2 + rr, 0, 2047);
        *(float2*)&simg[rr * 108 + 2 * c2] =
            *(const float2*)&img[(size_t)qy * 6144 + (size_t)(x0 - 2) * 3 +
                                 2 * c2];
      }
    } else {  // x-edge blocks: scalar with per-pixel clamp (mode='nearest'
              // values are never selected; clamp only keeps reads in-bounds)
      for (int e = threadIdx.x; e < 1296; e += 256) {
        int rr = e / 108, c3 = e - rr * 108;
        int col = c3 / 3, ch = c3 - col * 3;
        int qy = clampi(y0 - 2 + rr, 0, 2047);
        int qx = clampi(x0 - 2 + col, 0, 2047);
        simg[e] = img[((size_t)qy * Ww + qx) * 3 + ch];
      }
    }
    __syncthreads();

    unsigned w[4][4];
#pragma unroll
    for (int dyi = 0; dyi < 4; ++dyi)
#pragma unroll
      for (int dxi = 0; dxi < 4; ++dxi)
        w[dyi][dxi] = sh[(ty + dyi) * HX + (tx + dxi)];

    int loff = 0;  // local offset into simg (36-wide rows)
#define CANDC(dyi, dxi) ((unsigned)((1 - (dxi)) + 2) | ((unsigned)((1 - (dyi)) + 2) << 8))
#define LOFFC(dyi, dxi) (-(1 - (dyi)) * 36 - (1 - (dxi)))
#define CAND0(dyi, dxi) \
  if ((w[dyi][dxi] & 0xFFFFu) == CANDC(dyi, dxi)) loff = LOFFC(dyi, dxi);
#define CAND1(dyi, dxi) \
  if ((w[dyi][dxi] >> 16) == CANDC(dyi, dxi)) loff = LOFFC(dyi, dxi);

    // i = 0 write2 candidates, in increasing-order sequence
    CAND0(0, 0) CAND0(0, 1) CAND0(0, 2) CAND0(0, 3)
    CAND0(1, 0) CAND0(1, 1) CAND0(1, 2) CAND0(1, 3)
    CAND0(2, 0) CAND0(2, 1) CAND0(2, 2) CAND0(2, 3)
    CAND0(3, 0) CAND0(3, 1) CAND0(3, 2) CAND0(3, 3)
    // i = 1: cands with ddy*REG+ddx >= 1, then self-write, then the rest
    CAND1(0, 0) CAND1(0, 1) CAND1(0, 2) CAND1(0, 3)
    CAND1(1, 0)
    {  // self-write (i=1 write1): src = p + off1[p]
      unsigned wc = w[1][1];
      if ((wc >> 24) != 0xFFu) {
        int dh1 = (int)((wc >> 24) & 0xFFu) - 2;
        int dw1 = (int)((wc >> 16) & 0xFFu) - 2;
        loff = dh1 * 36 + dw1;
      }
    }
    CAND1(1, 1) CAND1(1, 2) CAND1(1, 3)
    CAND1(2, 0) CAND1(2, 1) CAND1(2, 2) CAND1(2, 3)
    CAND1(3, 0) CAND1(3, 1) CAND1(3, 2) CAND1(3, 3)
#undef CANDC
#undef LOFFC
#undef CAND0
#undef CAND1

    int L = ((ty + 2) * 36 + (tx + 2) + loff) * 3;
    r = simg[L + 0];
    g = simg[L + 1];
    b = simg[L + 2];
  } else {
    // shell between SKIP and SWAP circles: plain convert
    r = img[(size_t)plin * 3 + 0];
    g = img[(size_t)plin * 3 + 1];
    b = img[(size_t)plin * 3 + 2];
  }
  A[plin] = __float2half(r);
  A[HW + plin] = __float2half(g);
  A[2 * HW + plin] = __float2half(b);
}

// ---------------------------------------------------------------------------
// Pass 2 (fused blur + compose).
// Round-7: R5's exact geometry + traffic profile (BTH=16, FETCH 24 MB, WRITE
// 49 MB, 0 conflicts — proven) but 512 threads per tile-block. Per-thread
// state halves (br[3][2][2]=12 floats) -> VGPR target <=64 pinned via
// __launch_bounds__(512,8) -> 8 waves/SIMD tier, 4 blocks/CU = 32 waves/CU
// nominal (R5: 16). R6's BTH=8 route is dead: it tripled staging rows and
// concurrent footprint, un-merging the stride-24 out stores in L2 (WRITE
// 49->153 MB RMW amplification).
// ---------------------------------------------------------------------------
constexpr int BTW = 128, BTH = 16;  // output tile
constexpr int SW = BTW + 16;        // 144 staged cols
constexpr int SH = BTH + 16;        // 32 staged rows

// Per-tile-column clean-interval tables (exact, from CLEAN_D2 circle):
// heavy counts/col: {128,128,128,76,58,46,38,34,34,38,46,58,76,128,128,128}
__device__ __constant__ short HPRE[17] = {0,   128, 256, 384, 460,  518,
                                          564, 602, 636, 670, 708,  754,
                                          812, 888, 1016, 1144, 1272};
__device__ __constant__ short CPRE[17] = {0,   0,   0,   0,   52,  122,
                                          204, 294, 388, 482, 572, 654,
                                          724, 776, 776, 776, 776};
__device__ __constant__ short CLO[16] = {128, 128, 128, 38, 29, 23, 19, 17,
                                         17,  19,  23,  29, 38, 128, 128, 128};
__device__ __constant__ short CCN[16] = {0,  0,  0,  52, 70, 82, 90, 94,
                                         94, 90, 82, 70, 52, 0,  0,  0};
constexpr int NHEAVY = 1272;  // = 8 * 159
constexpr int NCLEAN = 776;   // = 8 * 97

__global__ __launch_bounds__(512, 8) void blur_compose(
    const __half* __restrict__ A, const float* __restrict__ img,
    float* __restrict__ out) {
  int lin = blockIdx.x;  // 2048 = NHEAVY + NCLEAN
  int tid = threadIdx.x;
  int txb, tyb;
  bool is_clean = lin >= NHEAVY;
  if (!is_clean) {
    int idx = (lin & 7) * 159 + (lin >> 3);  // XCD k: heavy run [159k,159k+159)
    int c = 0;
    while (idx >= HPRE[c + 1]) ++c;
    int j = idx - HPRE[c];
    txb = c;
    tyb = j < CLO[c] ? j : j + CCN[c];  // skip the clean interval
  } else {
    int l = lin - NHEAVY;
    int idx = (l & 7) * 97 + (l >> 3);
    int c = 0;
    while (idx >= CPRE[c + 1]) ++c;
    txb = c;
    tyb = CLO[c] + (idx - CPRE[c]);
  }
  int x0 = txb * BTW, y0 = tyb * BTH;

  // Clean tile: straight float4 copy, A never touched.
  if (is_clean) {
    const float4* ip = (const float4*)(img + ((size_t)y0 * Ww + x0) * 3);
    float4* op = (float4*)(out + ((size_t)y0 * Ww + x0) * 3);
#pragma unroll
    for (int k = 0; k < 3; ++k) {  // 16 rows x 96 float4 = 1536, exact
      int e = tid + (k << 9);
      int rr = e / 96, c4 = e - rr * 96;
      op[(size_t)rr * 1536 + c4] = ip[(size_t)rr * 1536 + c4];
    }
    return;
  }

  __shared__ __align__(16) __half S[SH * SW];  // 9.2 KB staged A (half)
  __shared__ __align__(8) __half V[BTH * SW];  // 4.6 KB vertical result (half)

  bool xin = (x0 >= 8) && (x0 + SW - 8 <= Ww);  // no x clamp needed

  float br[3][2][2];  // [channel][pair-slot][pixel-in-pair]

  for (int c = 0; c < 3; ++c) {
    const __half* Ap = A + (size_t)c * HW;
    // ---- stage A tile+halo ----
    // (safe without a leading barrier: previous channel's S readers are all
    //  behind the post-vertical barrier; horizontal only touches V.)
    if (xin) {
      for (int e = tid; e < SH * 18; e += 512) {  // 18 dwordx4 per row
        int rr = e / 18, ch = e - rr * 18;
        int ys = clampi(y0 - 8 + rr, 0, Hh - 1);  // mode='nearest'
        *(uint4*)&S[rr * SW + ch * 8] =
            *(const uint4*)&Ap[(size_t)ys * Ww + (x0 - 8) + ch * 8];
      }
    } else {
      for (int e = tid; e < SH * SW; e += 512) {
        int rr = e / SW, j = e - rr * SW;
        int ys = clampi(y0 - 8 + rr, 0, Hh - 1);
        int xs = clampi(x0 - 8 + j, 0, Ww - 1);
        S[e] = Ap[(size_t)ys * Ww + xs];
      }
    }
    __syncthreads();  // S staged, and prev channel's V readers done
    // ---- vertical 17-tap: 16 rows x 72 half2 cols = 1152 items ----
    for (int e = tid; e < BTH * 72; e += 512) {
      int rr = e / 72, p = e - rr * 72;
      float s0 = 0.f, s1 = 0.f;
#pragma unroll
      for (int t = 0; t < 17; ++t) {
        float2 v = __half22float2(*(const __half2*)&S[(rr + t) * SW + 2 * p]);
        s0 += GK[t] * v.x;
        s1 += GK[t] * v.y;
      }
      *(__half2*)&V[rr * SW + 2 * p] = __float22half2_rn(make_float2(s0, s1));
    }
    __syncthreads();
    // ---- horizontal 17-tap into registers: 16 rows x 64 px-pairs ----
#pragma unroll
    for (int k = 0; k < 2; ++k) {
      int e = tid + (k << 9);  // 0..1023, exact
      int rr = e >> 6, x = (e & 63) * 2;
      float f[18];
#pragma unroll
      for (int t = 0; t < 9; ++t) {
        float2 v = __half22float2(*(const __half2*)&V[rr * SW + x + 2 * t]);
        f[2 * t] = v.x;
        f[2 * t + 1] = v.y;
      }
      float s0 = 0.f, s1 = 0.f;
#pragma unroll
      for (int t = 0; t < 17; ++t) {
        s0 += GK[t] * f[t];
        s1 += GK[t] * f[t + 1];
      }
      br[c][k][0] = s0;
      br[c][k][1] = s1;
    }
  }

  // ---- single write phase: 24 contiguous bytes per pixel-pair ----
#pragma unroll
  for (int k = 0; k < 2; ++k) {
    int e = tid + (k << 9);
    int rr = e >> 6, xh = e & 63;
    int y = y0 + rr;
    int xg = x0 + 2 * xh;
    int dy = 1024 - y;
    int dy2 = dy * dy;
    float px[6];
#pragma unroll
    for (int u = 0; u < 2; ++u) {
      int xu = xg + u;
      int dx = 1024 - xu;
      bool clean = (xu >= 2 && xu <= 2046 && y >= 2 && y <= 2046 &&
                    dx * dx + dy2 < CLEAN_D2);
      int p3 = (y * Ww + xu) * 3;
      if (clean) {
        px[3 * u + 0] = img[p3 + 0];
        px[3 * u + 1] = img[p3 + 1];
        px[3 * u + 2] = img[p3 + 2];
      } else {
#pragma unroll
        for (int cc = 0; cc < 3; ++cc) {
          float v = br[cc][k][u];
          v = v < 0.f ? 0.f : (v > 255.f ? 255.f : v);
          px[3 * u + cc] = v;
        }
      }
    }
    float* ob = out + (size_t)(y * Ww + xg) * 3;
    *(float2*)&ob[0] = make_float2(px[0], px[1]);
    *(float2*)&ob[2] = make_float2(px[2], px[3]);
    *(float2*)&ob[4] = make_float2(px[4], px[5]);
  }
}

extern "C" void kernel_launch(void* const* d_in, const int* in_sizes, int n_in,
                              void* d_out, int out_size, void* d_ws,
                              size_t ws_size, hipStream_t stream) {
  const float* img = (const float*)d_in[0];
  const int* off = (const int*)d_in[1];
  float* out = (float*)d_out;

  // Workspace: A (fp16 x 3 planes, 25 MB)
  __half* A = (__half*)d_ws;

  swap_gather<<<dim3(Ww / TX, Hh / TY), 256, 0, stream>>>(img, off, A);
  blur_compose<<<NHEAVY + NCLEAN, 512, 0, stream>>>(A, img, out);
}

// Round 8
// 208.164 us; speedup vs baseline: 1.1122x; 1.0097x over previous
//
#include <hip/hip_runtime.h>
#include <hip/hip_fp16.h>

// Problem constants (H=W=2048, C=3, KSIZE=2, SIGMA=2, ITERATIONS=2)
#define Hh 2048
#define Ww 2048
#define HW (2048 * 2048)
constexpr int REG = 2045;              // Hv = Wv = H - 2*KSIZE + 1
constexpr int RBASE = 2 * 2045 * 2045; // i-plane stride of `off` in elements
constexpr int SWAP_D2 = 589824;        // 768^2
constexpr int CLEAN_D2 = 586756;       // 766^2
// A[p] is consumed by some non-clean blur output iff dist(p) >= 766 - 8*sqrt(2)
// = 754.686 (754.686^2 = 569551). Blocks strictly inside this circle can skip
// everything: their A values only ever contribute to outputs that compose
// SELECTS (not blends) from img, so even NaN garbage is harmless.
constexpr int SKIP_D2 = 569000;

// Gaussian kernel sigma=2, truncate=4 -> radius 8, normalized (precomputed)
__device__ __constant__ float GK[17] = {
    6.691628e-05f, 4.363490e-04f, 2.215963e-03f, 8.764304e-03f,
    2.699596e-02f, 6.475994e-02f, 1.209875e-01f, 1.760358e-01f,
    1.9947466e-01f, 1.760358e-01f, 1.209875e-01f, 6.475994e-02f,
    2.699596e-02f, 8.764304e-03f, 2.215963e-03f, 4.363490e-04f,
    6.691628e-05f};

__device__ __forceinline__ int clampi(int v, int lo, int hi) {
  return v < lo ? lo : (v > hi ? hi : v);
}

// ---------------------------------------------------------------------------
// Pass 1: gather-formulated glass swap + fp16 planar repack (unchanged).
// ---------------------------------------------------------------------------
constexpr int TX = 32, TY = 8;
constexpr int HX = TX + 3, HY = TY + 3;  // 35 x 11 offsets halo

__global__ __launch_bounds__(256) void swap_gather(
    const float* __restrict__ img, const int* __restrict__ off,
    __half* __restrict__ A) {
  __shared__ unsigned sh[HY * HX];
  __shared__ __align__(16) float simg[12 * 108];  // 12 rows x 36 px x 3 ch
  int x0 = blockIdx.x * TX, y0 = blockIdx.y * TY;
  int tx = threadIdx.x & 31, ty = threadIdx.x >> 5;
  int px = x0 + tx, py = y0 + ty;
  int plin = py * Ww + px;

  // Deep clean interior: A never consumed -> skip the whole block.
  int bxx = max(abs(1024 - x0), abs(1024 - (x0 + TX - 1)));
  int bxy = max(abs(1024 - y0), abs(1024 - (y0 + TY - 1)));
  if (bxx * bxx + bxy * bxy < SKIP_D2) return;

  float r, g, b;
  int mxx = max(abs(1024 - (x0 - 1)), abs(1024 - (x0 + TX + 1)));
  int mxy = max(abs(1024 - (y0 - 1)), abs(1024 - (y0 + TY + 1)));
  if (mxx * mxx + mxy * mxy >= SWAP_D2) {
    // ---- stage packed offsets halo (rows y0-1..y0+9, cols x0-1..x0+33) ----
    for (int e = threadIdx.x; e < HY * HX; e += 256) {
      int ly = e / HX, lx = e - ly * HX;
      int qy = y0 - 1 + ly, qx = x0 - 1 + lx;
      unsigned v = 0xFFFFFFFFu;
      int dcx = 1024 - qx, dcy = 1024 - qy;
      if (qy >= 2 && qy <= 2046 && qx >= 2 && qx <= 2046 &&
          dcx * dcx + dcy * dcy >= SWAP_D2) {
        int base = ((qy - 2) * REG + (qx - 2)) * 2;
        const int2 a0 = *(const int2*)&off[base];          // {dh0, dw0}
        const int2 a1 = *(const int2*)&off[RBASE + base];  // {dh1, dw1}
        v = (unsigned)(a0.y + 2) | ((unsigned)(a0.x + 2) << 8) |
            ((unsigned)(a1.y + 2) << 16) | ((unsigned)(a1.x + 2) << 24);
      }
      sh[e] = v;
    }
    // ---- stage img halo (rows y0-2..y0+9, cols x0-2..x0+33, 3 ch) ----
    if (x0 >= 2 && x0 <= 2013) {  // interior in x: coalesced float2 rows
      for (int e = threadIdx.x; e < 648; e += 256) {
        int rr = e / 54, c2 = e - rr * 54;
        int qy = clampi(y0 - 2 + rr, 0, 2047);
        *(float2*)&simg[rr * 108 + 2 * c2] =
            *(const float2*)&img[(size_t)qy * 6144 + (size_t)(x0 - 2) * 3 +
                                 2 * c2];
      }
    } else {  // x-edge blocks: scalar with per-pixel clamp (mode='nearest'
              // values are never selected; clamp only keeps reads in-bounds)
      for (int e = threadIdx.x; e < 1296; e += 256) {
        int rr = e / 108, c3 = e - rr * 108;
        int col = c3 / 3, ch = c3 - col * 3;
        int qy = clampi(y0 - 2 + rr, 0, 2047);
        int qx = clampi(x0 - 2 + col, 0, 2047);
        simg[e] = img[((size_t)qy * Ww + qx) * 3 + ch];
      }
    }
    __syncthreads();

    unsigned w[4][4];
#pragma unroll
    for (int dyi = 0; dyi < 4; ++dyi)
#pragma unroll
      for (int dxi = 0; dxi < 4; ++dxi)
        w[dyi][dxi] = sh[(ty + dyi) * HX + (tx + dxi)];

    int loff = 0;  // local offset into simg (36-wide rows)
#define CANDC(dyi, dxi) ((unsigned)((1 - (dxi)) + 2) | ((unsigned)((1 - (dyi)) + 2) << 8))
#define LOFFC(dyi, dxi) (-(1 - (dyi)) * 36 - (1 - (dxi)))
#define CAND0(dyi, dxi) \
  if ((w[dyi][dxi] & 0xFFFFu) == CANDC(dyi, dxi)) loff = LOFFC(dyi, dxi);
#define CAND1(dyi, dxi) \
  if ((w[dyi][dxi] >> 16) == CANDC(dyi, dxi)) loff = LOFFC(dyi, dxi);

    // i = 0 write2 candidates, in increasing-order sequence
    CAND0(0, 0) CAND0(0, 1) CAND0(0, 2) CAND0(0, 3)
    CAND0(1, 0) CAND0(1, 1) CAND0(1, 2) CAND0(1, 3)
    CAND0(2, 0) CAND0(2, 1) CAND0(2, 2) CAND0(2, 3)
    CAND0(3, 0) CAND0(3, 1) CAND0(3, 2) CAND0(3, 3)
    // i = 1: cands with ddy*REG+ddx >= 1, then self-write, then the rest
    CAND1(0, 0) CAND1(0, 1) CAND1(0, 2) CAND1(0, 3)
    CAND1(1, 0)
    {  // self-write (i=1 write1): src = p + off1[p]
      unsigned wc = w[1][1];
      if ((wc >> 24) != 0xFFu) {
        int dh1 = (int)((wc >> 24) & 0xFFu) - 2;
        int dw1 = (int)((wc >> 16) & 0xFFu) - 2;
        loff = dh1 * 36 + dw1;
      }
    }
    CAND1(1, 1) CAND1(1, 2) CAND1(1, 3)
    CAND1(2, 0) CAND1(2, 1) CAND1(2, 2) CAND1(2, 3)
    CAND1(3, 0) CAND1(3, 1) CAND1(3, 2) CAND1(3, 3)
#undef CANDC
#undef LOFFC
#undef CAND0
#undef CAND1

    int L = ((ty + 2) * 36 + (tx + 2) + loff) * 3;
    r = simg[L + 0];
    g = simg[L + 1];
    b = simg[L + 2];
  } else {
    // shell between SKIP and SWAP circles: plain convert
    r = img[(size_t)plin * 3 + 0];
    g = img[(size_t)plin * 3 + 1];
    b = img[(size_t)plin * 3 + 2];
  }
  A[plin] = __float2half(r);
  A[HW + plin] = __float2half(g);
  A[2 * HW + plin] = __float2half(b);
}

// ---------------------------------------------------------------------------
// Pass 2 (fused blur + compose).
// Round-8: R7 (512 thr, VGPR 32, occupancy 58%) + STRUCTURALLY line-coherent
// out stores. R7's stride-24 per-lane float2 stores relied on L2 write-
// combining; at 32 waves/CU the concurrent footprint exceeds 4 MB/XCD L2 and
// partial lines spill -> RMW (WRITE 49->122 MB, FETCH 24->58 MB, both R6/R7).
// Fix: compose into an LDS tile O (16 x 384 f32, aliased over dead S/V),
// barrier, store as stride-1 float4 (64B line = 4 consecutive lanes, one
// instruction) — immune to L2 pressure.
// ---------------------------------------------------------------------------
constexpr int BTW = 128, BTH = 16;  // output tile
constexpr int SW = BTW + 16;        // 144 staged cols
constexpr int SH = BTH + 16;        // 32 staged rows

// Per-tile-column clean-interval tables (exact, from CLEAN_D2 circle):
// heavy counts/col: {128,128,128,76,58,46,38,34,34,38,46,58,76,128,128,128}
__device__ __constant__ short HPRE[17] = {0,   128, 256, 384, 460,  518,
                                          564, 602, 636, 670, 708,  754,
                                          812, 888, 1016, 1144, 1272};
__device__ __constant__ short CPRE[17] = {0,   0,   0,   0,   52,  122,
                                          204, 294, 388, 482, 572, 654,
                                          724, 776, 776, 776, 776};
__device__ __constant__ short CLO[16] = {128, 128, 128, 38, 29, 23, 19, 17,
                                         17,  19,  23,  29, 38, 128, 128, 128};
__device__ __constant__ short CCN[16] = {0,  0,  0,  52, 70, 82, 90, 94,
                                         94, 90, 82, 70, 52, 0,  0,  0};
constexpr int NHEAVY = 1272;  // = 8 * 159
constexpr int NCLEAN = 776;   // = 8 * 97

__global__ __launch_bounds__(512, 8) void blur_compose(
    const __half* __restrict__ A, const float* __restrict__ img,
    float* __restrict__ out) {
  int lin = blockIdx.x;  // 2048 = NHEAVY + NCLEAN
  int tid = threadIdx.x;
  int txb, tyb;
  bool is_clean = lin >= NHEAVY;
  if (!is_clean) {
    int idx = (lin & 7) * 159 + (lin >> 3);  // XCD k: heavy run [159k,159k+159)
    int c = 0;
    while (idx >= HPRE[c + 1]) ++c;
    int j = idx - HPRE[c];
    txb = c;
    tyb = j < CLO[c] ? j : j + CCN[c];  // skip the clean interval
  } else {
    int l = lin - NHEAVY;
    int idx = (l & 7) * 97 + (l >> 3);
    int c = 0;
    while (idx >= CPRE[c + 1]) ++c;
    txb = c;
    tyb = CLO[c] + (idx - CPRE[c]);
  }
  int x0 = txb * BTW, y0 = tyb * BTH;

  // Clean tile: straight float4 copy, A never touched.
  if (is_clean) {
    const float4* ip = (const float4*)(img + ((size_t)y0 * Ww + x0) * 3);
    float4* op = (float4*)(out + ((size_t)y0 * Ww + x0) * 3);
#pragma unroll
    for (int k = 0; k < 3; ++k) {  // 16 rows x 96 float4 = 1536, exact
      int e = tid + (k << 9);
      int rr = e / 96, c4 = e - rr * 96;
      op[(size_t)rr * 1536 + c4] = ip[(size_t)rr * 1536 + c4];
    }
    return;
  }

  // LDS: S (9216 B) + V (4608 B) live during the channel loop; O (24576 B)
  // aliases them for the write phase (S/V dead by then, barrier-separated).
  __shared__ __align__(16) unsigned char lds_raw[BTH * BTW * 3 * 4];
  __half* S = (__half*)lds_raw;                      // [SH][SW]
  __half* V = (__half*)(lds_raw + SH * SW * 2);      // [BTH][SW]
  float* O = (float*)lds_raw;                        // [BTH][384]

  bool xin = (x0 >= 8) && (x0 + SW - 8 <= Ww);  // no x clamp needed

  float br[3][2][2];  // [channel][pair-slot][pixel-in-pair]

  for (int c = 0; c < 3; ++c) {
    const __half* Ap = A + (size_t)c * HW;
    // ---- stage A tile+halo ----
    // (safe without a leading barrier: previous channel's S readers are all
    //  behind the post-vertical barrier; horizontal only touches V.)
    if (xin) {
      for (int e = tid; e < SH * 18; e += 512) {  // 18 dwordx4 per row
        int rr = e / 18, ch = e - rr * 18;
        int ys = clampi(y0 - 8 + rr, 0, Hh - 1);  // mode='nearest'
        *(uint4*)&S[rr * SW + ch * 8] =
            *(const uint4*)&Ap[(size_t)ys * Ww + (x0 - 8) + ch * 8];
      }
    } else {
      for (int e = tid; e < SH * SW; e += 512) {
        int rr = e / SW, j = e - rr * SW;
        int ys = clampi(y0 - 8 + rr, 0, Hh - 1);
        int xs = clampi(x0 - 8 + j, 0, Ww - 1);
        S[e] = Ap[(size_t)ys * Ww + xs];
      }
    }
    __syncthreads();  // S staged, and prev channel's V readers done
    // ---- vertical 17-tap: 16 rows x 72 half2 cols = 1152 items ----
    for (int e = tid; e < BTH * 72; e += 512) {
      int rr = e / 72, p = e - rr * 72;
      float s0 = 0.f, s1 = 0.f;
#pragma unroll
      for (int t = 0; t < 17; ++t) {
        float2 v = __half22float2(*(const __half2*)&S[(rr + t) * SW + 2 * p]);
        s0 += GK[t] * v.x;
        s1 += GK[t] * v.y;
      }
      *(__half2*)&V[rr * SW + 2 * p] = __float22half2_rn(make_float2(s0, s1));
    }
    __syncthreads();
    // ---- horizontal 17-tap into registers: 16 rows x 64 px-pairs ----
#pragma unroll
    for (int k = 0; k < 2; ++k) {
      int e = tid + (k << 9);  // 0..1023, exact
      int rr = e >> 6, x = (e & 63) * 2;
      float f[18];
#pragma unroll
      for (int t = 0; t < 9; ++t) {
        float2 v = __half22float2(*(const __half2*)&V[rr * SW + x + 2 * t]);
        f[2 * t] = v.x;
        f[2 * t + 1] = v.y;
      }
      float s0 = 0.f, s1 = 0.f;
#pragma unroll
      for (int t = 0; t < 17; ++t) {
        s0 += GK[t] * f[t];
        s1 += GK[t] * f[t + 1];
      }
      br[c][k][0] = s0;
      br[c][k][1] = s1;
    }
  }

  __syncthreads();  // all V reads done before O overwrites S/V

  // ---- compose into LDS O tile ----
#pragma unroll
  for (int k = 0; k < 2; ++k) {
    int e = tid + (k << 9);
    int rr = e >> 6, xh = e & 63;
    int y = y0 + rr;
    int xg = x0 + 2 * xh;
    int dy = 1024 - y;
    int dy2 = dy * dy;
    float* orow = O + rr * 384 + xh * 6;
#pragma unroll
    for (int u = 0; u < 2; ++u) {
      int xu = xg + u;
      int dx = 1024 - xu;
      bool clean = (xu >= 2 && xu <= 2046 && y >= 2 && y <= 2046 &&
                    dx * dx + dy2 < CLEAN_D2);
      int p3 = (y * Ww + xu) * 3;
      if (clean) {
        orow[3 * u + 0] = img[p3 + 0];
        orow[3 * u + 1] = img[p3 + 1];
        orow[3 * u + 2] = img[p3 + 2];
      } else {
#pragma unroll
        for (int cc = 0; cc < 3; ++cc) {
          float v = br[cc][k][u];
          v = v < 0.f ? 0.f : (v > 255.f ? 255.f : v);
          orow[3 * u + cc] = v;
        }
      }
    }
  }
  __syncthreads();

  // ---- line-coherent store: stride-1 float4, 16 rows x 96 per row ----
  {
    const float4* O4 = (const float4*)O;
    float4* op = (float4*)(out + ((size_t)y0 * Ww + x0) * 3);
#pragma unroll
    for (int k = 0; k < 3; ++k) {  // 1536 float4, exact
      int e = tid + (k << 9);
      int rr = e / 96, c4 = e - rr * 96;
      op[(size_t)rr * 1536 + c4] = O4[e];
    }
  }
}

extern "C" void kernel_launch(void* const* d_in, const int* in_sizes, int n_in,
                              void* d_out, int out_size, void* d_ws,
                              size_t ws_size, hipStream_t stream) {
  const float* img = (const float*)d_in[0];
  const int* off = (const int*)d_in[1];
  float* out = (float*)d_out;

  // Workspace: A (fp16 x 3 planes, 25 MB)
  __half* A = (__half*)d_ws;

  swap_gather<<<dim3(Ww / TX, Hh / TY), 256, 0, stream>>>(img, off, A);
  blur_compose<<<NHEAVY + NCLEAN, 512, 0, stream>>>(A, img, out);
}

// Round 9
// 184.999 us; speedup vs baseline: 1.2515x; 1.1252x over previous
//
#include <hip/hip_runtime.h>
#include <hip/hip_fp16.h>

// Problem constants (H=W=2048, C=3, KSIZE=2, SIGMA=2, ITERATIONS=2)
#define Hh 2048
#define Ww 2048
#define HW (2048 * 2048)
constexpr int REG = 2045;              // Hv = Wv = H - 2*KSIZE + 1
constexpr int RBASE = 2 * 2045 * 2045; // i-plane stride of `off` in elements
constexpr int SWAP_D2 = 589824;        // 768^2
constexpr int CLEAN_D2 = 586756;       // 766^2
// A[p] is consumed by some non-clean blur output iff dist(p) >= 766 - 8*sqrt(2)
// = 754.686 (754.686^2 = 569551). Blocks strictly inside this circle can skip
// everything: their A values only ever contribute to outputs that compose
// SELECTS (not blends) from img, so even NaN garbage is harmless.
constexpr int SKIP_D2 = 569000;

// Gaussian kernel sigma=2, truncate=4 -> radius 8, normalized (precomputed)
__device__ __constant__ float GK[17] = {
    6.691628e-05f, 4.363490e-04f, 2.215963e-03f, 8.764304e-03f,
    2.699596e-02f, 6.475994e-02f, 1.209875e-01f, 1.760358e-01f,
    1.9947466e-01f, 1.760358e-01f, 1.209875e-01f, 6.475994e-02f,
    2.699596e-02f, 8.764304e-03f, 2.215963e-03f, 4.363490e-04f,
    6.691628e-05f};

__device__ __forceinline__ int clampi(int v, int lo, int hi) {
  return v < lo ? lo : (v > hi ? hi : v);
}

// ---------------------------------------------------------------------------
// Pass 1: gather-formulated glass swap + fp16 planar repack (unchanged).
// ---------------------------------------------------------------------------
constexpr int TX = 32, TY = 8;
constexpr int HX = TX + 3, HY = TY + 3;  // 35 x 11 offsets halo

__global__ __launch_bounds__(256) void swap_gather(
    const float* __restrict__ img, const int* __restrict__ off,
    __half* __restrict__ A) {
  __shared__ unsigned sh[HY * HX];
  __shared__ __align__(16) float simg[12 * 108];  // 12 rows x 36 px x 3 ch
  int x0 = blockIdx.x * TX, y0 = blockIdx.y * TY;
  int tx = threadIdx.x & 31, ty = threadIdx.x >> 5;
  int px = x0 + tx, py = y0 + ty;
  int plin = py * Ww + px;

  // Deep clean interior: A never consumed -> skip the whole block.
  int bxx = max(abs(1024 - x0), abs(1024 - (x0 + TX - 1)));
  int bxy = max(abs(1024 - y0), abs(1024 - (y0 + TY - 1)));
  if (bxx * bxx + bxy * bxy < SKIP_D2) return;

  float r, g, b;
  int mxx = max(abs(1024 - (x0 - 1)), abs(1024 - (x0 + TX + 1)));
  int mxy = max(abs(1024 - (y0 - 1)), abs(1024 - (y0 + TY + 1)));
  if (mxx * mxx + mxy * mxy >= SWAP_D2) {
    // ---- stage packed offsets halo (rows y0-1..y0+9, cols x0-1..x0+33) ----
    for (int e = threadIdx.x; e < HY * HX; e += 256) {
      int ly = e / HX, lx = e - ly * HX;
      int qy = y0 - 1 + ly, qx = x0 - 1 + lx;
      unsigned v = 0xFFFFFFFFu;
      int dcx = 1024 - qx, dcy = 1024 - qy;
      if (qy >= 2 && qy <= 2046 && qx >= 2 && qx <= 2046 &&
          dcx * dcx + dcy * dcy >= SWAP_D2) {
        int base = ((qy - 2) * REG + (qx - 2)) * 2;
        const int2 a0 = *(const int2*)&off[base];          // {dh0, dw0}
        const int2 a1 = *(const int2*)&off[RBASE + base];  // {dh1, dw1}
        v = (unsigned)(a0.y + 2) | ((unsigned)(a0.x + 2) << 8) |
            ((unsigned)(a1.y + 2) << 16) | ((unsigned)(a1.x + 2) << 24);
      }
      sh[e] = v;
    }
    // ---- stage img halo (rows y0-2..y0+9, cols x0-2..x0+33, 3 ch) ----
    if (x0 >= 2 && x0 <= 2013) {  // interior in x: coalesced float2 rows
      for (int e = threadIdx.x; e < 648; e += 256) {
        int rr = e / 54, c2 = e - rr * 54;
        int qy = clampi(y0 - 2 + rr, 0, 2047);
        *(float2*)&simg[rr * 108 + 2 * c2] =
            *(const float2*)&img[(size_t)qy * 6144 + (size_t)(x0 - 2) * 3 +
                                 2 * c2];
      }
    } else {  // x-edge blocks: scalar with per-pixel clamp (mode='nearest'
              // values are never selected; clamp only keeps reads in-bounds)
      for (int e = threadIdx.x; e < 1296; e += 256) {
        int rr = e / 108, c3 = e - rr * 108;
        int col = c3 / 3, ch = c3 - col * 3;
        int qy = clampi(y0 - 2 + rr, 0, 2047);
        int qx = clampi(x0 - 2 + col, 0, 2047);
        simg[e] = img[((size_t)qy * Ww + qx) * 3 + ch];
      }
    }
    __syncthreads();

    unsigned w[4][4];
#pragma unroll
    for (int dyi = 0; dyi < 4; ++dyi)
#pragma unroll
      for (int dxi = 0; dxi < 4; ++dxi)
        w[dyi][dxi] = sh[(ty + dyi) * HX + (tx + dxi)];

    int loff = 0;  // local offset into simg (36-wide rows)
#define CANDC(dyi, dxi) ((unsigned)((1 - (dxi)) + 2) | ((unsigned)((1 - (dyi)) + 2) << 8))
#define LOFFC(dyi, dxi) (-(1 - (dyi)) * 36 - (1 - (dxi)))
#define CAND0(dyi, dxi) \
  if ((w[dyi][dxi] & 0xFFFFu) == CANDC(dyi, dxi)) loff = LOFFC(dyi, dxi);
#define CAND1(dyi, dxi) \
  if ((w[dyi][dxi] >> 16) == CANDC(dyi, dxi)) loff = LOFFC(dyi, dxi);

    // i = 0 write2 candidates, in increasing-order sequence
    CAND0(0, 0) CAND0(0, 1) CAND0(0, 2) CAND0(0, 3)
    CAND0(1, 0) CAND0(1, 1) CAND0(1, 2) CAND0(1, 3)
    CAND0(2, 0) CAND0(2, 1) CAND0(2, 2) CAND0(2, 3)
    CAND0(3, 0) CAND0(3, 1) CAND0(3, 2) CAND0(3, 3)
    // i = 1: cands with ddy*REG+ddx >= 1, then self-write, then the rest
    CAND1(0, 0) CAND1(0, 1) CAND1(0, 2) CAND1(0, 3)
    CAND1(1, 0)
    {  // self-write (i=1 write1): src = p + off1[p]
      unsigned wc = w[1][1];
      if ((wc >> 24) != 0xFFu) {
        int dh1 = (int)((wc >> 24) & 0xFFu) - 2;
        int dw1 = (int)((wc >> 16) & 0xFFu) - 2;
        loff = dh1 * 36 + dw1;
      }
    }
    CAND1(1, 1) CAND1(1, 2) CAND1(1, 3)
    CAND1(2, 0) CAND1(2, 1) CAND1(2, 2) CAND1(2, 3)
    CAND1(3, 0) CAND1(3, 1) CAND1(3, 2) CAND1(3, 3)
#undef CANDC
#undef LOFFC
#undef CAND0
#undef CAND1

    int L = ((ty + 2) * 36 + (tx + 2) + loff) * 3;
    r = simg[L + 0];
    g = simg[L + 1];
    b = simg[L + 2];
  } else {
    // shell between SKIP and SWAP circles: plain convert
    r = img[(size_t)plin * 3 + 0];
    g = img[(size_t)plin * 3 + 1];
    b = img[(size_t)plin * 3 + 2];
  }
  A[plin] = __float2half(r);
  A[HW + plin] = __float2half(g);
  A[2 * HW + plin] = __float2half(b);
}

// ---------------------------------------------------------------------------
// Pass 2 (fused blur + compose).
// Round-9: R5 skeleton (256 thr, 16-row tiles, exact remap, stride-24 stores
// -> WRITE exactly 49 MB) with the barrier chain shortened at the back:
// per-channel V buffers (V3) so horizontal+compose+store is ONE barrier-free
// finale computing all 3 channels per px-pair straight into 6 registers.
// This deletes the br[3][4][2] register array (what made R5 VGPR=76, 4 blk/
// CU): target <=64 VGPR pinned via __launch_bounds__(256,8) -> 8 blk/CU
// nominal, LDS 23 KB -> ~6 blk/CU. DIAGNOSTIC: if WRITE inflates >>49 MB
// again, wave-concurrency itself drives HBM amplification (R6/R7/R8 mystery)
// and 16 waves/CU becomes a hard constraint.
// ---------------------------------------------------------------------------
constexpr int BTW = 128, BTH = 16;  // output tile
constexpr int SW = BTW + 16;        // 144 staged cols
constexpr int SH = BTH + 16;        // 32 staged rows

// Per-tile-column clean-interval tables (exact, from CLEAN_D2 circle):
// heavy counts/col: {128,128,128,76,58,46,38,34,34,38,46,58,76,128,128,128}
__device__ __constant__ short HPRE[17] = {0,   128, 256, 384, 460,  518,
                                          564, 602, 636, 670, 708,  754,
                                          812, 888, 1016, 1144, 1272};
__device__ __constant__ short CPRE[17] = {0,   0,   0,   0,   52,  122,
                                          204, 294, 388, 482, 572, 654,
                                          724, 776, 776, 776, 776};
__device__ __constant__ short CLO[16] = {128, 128, 128, 38, 29, 23, 19, 17,
                                         17,  19,  23,  29, 38, 128, 128, 128};
__device__ __constant__ short CCN[16] = {0,  0,  0,  52, 70, 82, 90, 94,
                                         94, 90, 82, 70, 52, 0,  0,  0};
constexpr int NHEAVY = 1272;  // = 8 * 159
constexpr int NCLEAN = 776;   // = 8 * 97

__global__ __launch_bounds__(256, 8) void blur_compose(
    const __half* __restrict__ A, const float* __restrict__ img,
    float* __restrict__ out) {
  int lin = blockIdx.x;  // 2048 = NHEAVY + NCLEAN
  int tid = threadIdx.x;
  int txb, tyb;
  bool is_clean = lin >= NHEAVY;
  if (!is_clean) {
    int idx = (lin & 7) * 159 + (lin >> 3);  // XCD k: heavy run [159k,159k+159)
    int c = 0;
    while (idx >= HPRE[c + 1]) ++c;
    int j = idx - HPRE[c];
    txb = c;
    tyb = j < CLO[c] ? j : j + CCN[c];  // skip the clean interval
  } else {
    int l = lin - NHEAVY;
    int idx = (l & 7) * 97 + (l >> 3);
    int c = 0;
    while (idx >= CPRE[c + 1]) ++c;
    txb = c;
    tyb = CLO[c] + (idx - CPRE[c]);
  }
  int x0 = txb * BTW, y0 = tyb * BTH;

  // Clean tile: straight float4 copy, A never touched.
  if (is_clean) {
    const float4* ip = (const float4*)(img + ((size_t)y0 * Ww + x0) * 3);
    float4* op = (float4*)(out + ((size_t)y0 * Ww + x0) * 3);
    for (int e = tid; e < 1536; e += 256) {  // 16 rows x 96 float4
      int rr = e / 96, c4 = e - rr * 96;
      op[(size_t)rr * 1536 + c4] = ip[(size_t)rr * 1536 + c4];
    }
    return;
  }

  __shared__ __align__(16) __half S[SH * SW];       // 9.2 KB staged A (half)
  __shared__ __align__(8) __half V3[3 * BTH * SW];  // 13.8 KB vertical (half)

  bool xin = (x0 >= 8) && (x0 + SW - 8 <= Ww);  // no x clamp needed

  // ---- per channel: stage -> bar -> vertical -> bar ----
  for (int c = 0; c < 3; ++c) {
    const __half* Ap = A + (size_t)c * HW;
    if (xin) {
      for (int e = tid; e < SH * 18; e += 256) {  // 18 dwordx4 per row
        int rr = e / 18, ch = e - rr * 18;
        int ys = clampi(y0 - 8 + rr, 0, Hh - 1);  // mode='nearest'
        *(uint4*)&S[rr * SW + ch * 8] =
            *(const uint4*)&Ap[(size_t)ys * Ww + (x0 - 8) + ch * 8];
      }
    } else {
      for (int e = tid; e < SH * SW; e += 256) {
        int rr = e / SW, j = e - rr * SW;
        int ys = clampi(y0 - 8 + rr, 0, Hh - 1);
        int xs = clampi(x0 - 8 + j, 0, Ww - 1);
        S[e] = Ap[(size_t)ys * Ww + xs];
      }
    }
    __syncthreads();  // S staged (and prev channel's vertical done with S)
    // vertical 17-tap: 16 rows x 72 half2 cols = 1152 items
    __half* Vc = V3 + c * (BTH * SW);
    for (int e = tid; e < BTH * 72; e += 256) {
      int rr = e / 72, p = e - rr * 72;
      float s0 = 0.f, s1 = 0.f;
#pragma unroll
      for (int t = 0; t < 17; ++t) {
        float2 v = __half22float2(*(const __half2*)&S[(rr + t) * SW + 2 * p]);
        s0 += GK[t] * v.x;
        s1 += GK[t] * v.y;
      }
      *(__half2*)&Vc[rr * SW + 2 * p] = __float22half2_rn(make_float2(s0, s1));
    }
    __syncthreads();  // V3[c] complete; S free for next channel
  }

  // ---- barrier-free finale: horizontal + clip + compose + store ----
#pragma unroll
  for (int k = 0; k < 4; ++k) {
    int e = tid + (k << 8);  // 1024 px-pairs, exact
    int rr = e >> 6, xh = e & 63;
    int y = y0 + rr;
    int xg = x0 + 2 * xh;
    int dy = 1024 - y;
    int dy2 = dy * dy;
    float px[6];
#pragma unroll
    for (int c = 0; c < 3; ++c) {
      const __half* Vc = V3 + c * (BTH * SW);
      float f[18];
#pragma unroll
      for (int t = 0; t < 9; ++t) {
        float2 v =
            __half22float2(*(const __half2*)&Vc[rr * SW + 2 * xh + 2 * t]);
        f[2 * t] = v.x;
        f[2 * t + 1] = v.y;
      }
      float s0 = 0.f, s1 = 0.f;
#pragma unroll
      for (int t = 0; t < 17; ++t) {
        s0 += GK[t] * f[t];
        s1 += GK[t] * f[t + 1];
      }
      s0 = s0 < 0.f ? 0.f : (s0 > 255.f ? 255.f : s0);
      s1 = s1 < 0.f ? 0.f : (s1 > 255.f ? 255.f : s1);
      px[c] = s0;
      px[3 + c] = s1;
    }
#pragma unroll
    for (int u = 0; u < 2; ++u) {
      int xu = xg + u;
      int dx = 1024 - xu;
      bool clean = (xu >= 2 && xu <= 2046 && y >= 2 && y <= 2046 &&
                    dx * dx + dy2 < CLEAN_D2);
      if (clean) {
        int p3 = (y * Ww + xu) * 3;
        px[3 * u + 0] = img[p3 + 0];
        px[3 * u + 1] = img[p3 + 1];
        px[3 * u + 2] = img[p3 + 2];
      }
    }
    float* ob = out + (size_t)(y * Ww + xg) * 3;
    *(float2*)&ob[0] = make_float2(px[0], px[1]);
    *(float2*)&ob[2] = make_float2(px[2], px[3]);
    *(float2*)&ob[4] = make_float2(px[4], px[5]);
  }
}

extern "C" void kernel_launch(void* const* d_in, const int* in_sizes, int n_in,
                              void* d_out, int out_size, void* d_ws,
                              size_t ws_size, hipStream_t stream) {
  const float* img = (const float*)d_in[0];
  const int* off = (const int*)d_in[1];
  float* out = (float*)d_out;

  // Workspace: A (fp16 x 3 planes, 25 MB)
  __half* A = (__half*)d_ws;

  swap_gather<<<dim3(Ww / TX, Hh / TY), 256, 0, stream>>>(img, off, A);
  blur_compose<<<NHEAVY + NCLEAN, 256, 0, stream>>>(A, img, out);
}